// Round 9
// baseline (397.165 us; speedup 1.0000x reference)
//
#include <hip/hip_runtime.h>

#define NN 50000
#define NE 800000
#define C 128
#define OUTC 64
#define BN_EPS 1e-5f
#define INVN (1.0f / 50000.0f)
#define NBLK 49        // ceil(NN/1024)
#define NSH 8          // dst-range shards (= XCDs)
#define SHW (NN / NSH) // 6250 dst rows per shard
#define NCHUNK 256
#define CHUNK (NE / NCHUNK) // 3125 edges per chunk
#define FB 32          // fill2 blocks per shard

typedef __attribute__((ext_vector_type(8))) short bf16x8;
typedef __attribute__((ext_vector_type(4))) float f32x4;
typedef __attribute__((ext_vector_type(8))) unsigned short u16x8;

// round-to-nearest-even f32 -> bf16 (finite values)
__device__ __forceinline__ unsigned short f2bf(float f) {
    unsigned u = __float_as_uint(f);
    u += 0x7fffu + ((u >> 16) & 1u);
    return (unsigned short)(u >> 16);
}
__device__ __forceinline__ float bf2f(unsigned short s) {
    return __uint_as_float((unsigned)s << 16);
}

// ---------------- CSR build: counting sort with XCD-local shard partition ----------------

// per-chunk shard histogram: pc[chunk][shard]
__global__ __launch_bounds__(256) void pcount_kernel(const int* __restrict__ dstp, int* __restrict__ pc) {
    __shared__ int lc[8];
    int tid = threadIdx.x, mb = blockIdx.x;
    if (tid < 8) lc[tid] = 0;
    __syncthreads();
    int end = (mb + 1) * CHUNK;
    for (int e = mb * CHUNK + tid; e < end; e += 256)
        atomicAdd(&lc[dstp[e] / SHW], 1);
    __syncthreads();
    if (tid < 8) pc[mb * 8 + tid] = lc[tid];
}

// exclusive scan over 2048 (shard-major: i = g*NCHUNK + m) -> po[i]
__global__ __launch_bounds__(256) void pscan_kernel(const int* __restrict__ pc, int* __restrict__ po) {
    __shared__ int lds[256];
    int t = threadIdx.x;
    int v[8], s = 0;
    #pragma unroll
    for (int j = 0; j < 8; ++j) {
        int i = t * 8 + j;
        v[j] = pc[(i & (NCHUNK - 1)) * 8 + (i >> 8)];
        s += v[j];
    }
    lds[t] = s;
    __syncthreads();
    for (int off = 1; off < 256; off <<= 1) {
        int x = (t >= off) ? lds[t - off] : 0;
        __syncthreads();
        lds[t] += x;
        __syncthreads();
    }
    int excl = lds[t] - s;
    #pragma unroll
    for (int j = 0; j < 8; ++j) { po[t * 8 + j] = excl; excl += v[j]; }
}

// partition edges into shard segments (disjoint per (chunk,shard)); also per-dst counts
__global__ __launch_bounds__(256) void ppart_kernel(const int* __restrict__ srcp, const int* __restrict__ dstp,
                                                    const int* __restrict__ po,
                                                    unsigned long long* __restrict__ part, int* __restrict__ cnt) {
    __shared__ int base[8], ctr[8];
    int tid = threadIdx.x, mb = blockIdx.x;
    if (tid < 8) { base[tid] = po[tid * NCHUNK + mb]; ctr[tid] = 0; }
    __syncthreads();
    int end = (mb + 1) * CHUNK;
    for (int e = mb * CHUNK + tid; e < end; e += 256) {
        int d = dstp[e], s = srcp[e];
        atomicAdd(&cnt[d], 1);                       // fire-and-forget
        int g = d / SHW;
        int slot = atomicAdd(&ctr[g], 1);            // LDS
        part[(size_t)(base[g] + slot)] = ((unsigned long long)(unsigned)d << 32) | (unsigned)s;
    }
}

__global__ __launch_bounds__(256) void scan1_kernel(const int* __restrict__ cnt, int* __restrict__ rowptr,
                                                    float* __restrict__ dinv, int* __restrict__ bsum) {
    __shared__ int lds[256];
    int tid = threadIdx.x;
    int base = blockIdx.x * 1024 + tid * 4;
    int v[4];
    int s = 0;
    #pragma unroll
    for (int j = 0; j < 4; ++j) { int i = base + j; v[j] = (i < NN) ? cnt[i] : 0; s += v[j]; }
    lds[tid] = s;
    __syncthreads();
    for (int off = 1; off < 256; off <<= 1) {
        int x = (tid >= off) ? lds[tid - off] : 0;
        __syncthreads();
        lds[tid] += x;
        __syncthreads();
    }
    int excl = lds[tid] - s;
    #pragma unroll
    for (int j = 0; j < 4; ++j) {
        int i = base + j;
        if (i < NN) {
            rowptr[i] = excl;                       // local exclusive; block offset added in scan3
            dinv[i] = rsqrtf((float)(v[j] + 1));    // +1 self-loop
        }
        excl += v[j];
    }
    if (tid == 255) bsum[blockIdx.x] = lds[255];
}

// adds block offsets (inline 49-element scan of bsum), mirrors into wpos
__global__ __launch_bounds__(256) void scan3_kernel(const int* __restrict__ bsum, int* __restrict__ rowptr,
                                                    int* __restrict__ wpos) {
    __shared__ int boff;
    int tid = threadIdx.x;
    if (tid < 64) {
        int orig = (tid < NBLK) ? bsum[tid] : 0;
        int v = orig;
        #pragma unroll
        for (int off = 1; off < 64; off <<= 1) {
            int x = __shfl_up(v, off);
            if (tid >= off) v += x;
        }
        if (tid == (int)blockIdx.x) boff = v - orig;   // exclusive prefix at this block
    }
    __syncthreads();
    int off = boff;
    int base = blockIdx.x * 1024 + tid * 4;
    #pragma unroll
    for (int j = 0; j < 4; ++j) {
        int i = base + j;
        if (i < NN) { int r = rowptr[i] + off; rowptr[i] = r; wpos[i] = r; }
    }
    if (blockIdx.x == 0 && tid == 0) rowptr[NN] = NE;
}

// scatter src into CSR col; everything (segment read, wpos atomics, col writes) XCD-local
__global__ __launch_bounds__(256) void fill2_kernel(const unsigned long long* __restrict__ part,
                                                    const int* __restrict__ po,
                                                    int* __restrict__ wpos, int* __restrict__ col) {
    int g = blockIdx.x & 7, ib = blockIdx.x >> 3;
    int lo = po[g * NCHUNK];
    int hi = (g == 7) ? NE : po[(g + 1) * NCHUNK];
    for (int idx = lo + ib * 256 + threadIdx.x; idx < hi; idx += FB * 256) {
        unsigned long long pk = part[idx];
        int d = (int)(pk >> 32), s = (int)(pk & 0xffffffffu);
        int p = atomicAdd(&wpos[d], 1);
        col[p] = s;
    }
}

// ---------------- W pre-pack: bf16, MFMA B-fragment layout ----------------
// Wpk[mat][kt(4)][nt(8)][lane(64)][8 bf16]: lane holds W[kt*32 + (lane>>4)*8 + j][nt*16 + (lane&15)]
// mat 0 = W1, 1 = W2, 2 = [Wmu|Wls]

__global__ __launch_bounds__(256) void prep_kernel(const float* __restrict__ W1, const float* __restrict__ W2,
                                                   const float* __restrict__ Wmu, const float* __restrict__ Wls,
                                                   unsigned short* __restrict__ Wpk) {
    int idx = blockIdx.x * 256 + threadIdx.x;    // 0..6143
    if (idx >= 3 * 2048) return;
    int which = idx >> 11;
    int r = idx & 2047;
    int l = r & 63;
    int nt = (r >> 6) & 7;
    int kt = r >> 9;
    int m = l & 15, kg = l >> 4;
    int c = nt * 16 + m;
    bf16x8 o;
    #pragma unroll
    for (int j = 0; j < 8; ++j) {
        int k = kt * 32 + kg * 8 + j;
        float w;
        if (which == 0)      w = W1[k * 128 + c];
        else if (which == 1) w = W2[k * 128 + c];
        else                 w = (c < 64) ? Wmu[k * 64 + c] : Wls[k * 64 + (c - 64)];
        o[j] = (short)f2bf(w);
    }
    *(bf16x8*)&Wpk[(size_t)which * 16384 + (size_t)r * 8] = o;
}

// ---------------- GEMM: [N x 128] @ [128 x 128] via bf16 MFMA, f32 accum ----------------
// TRANS: input is bf16 aggb; apply BN(from raw sums)+ReLU in f32, re-encode bf16
// !TRANS: input is f32 x
// Output: t[row][c] = bf16(dinv[row] * acc)  (pre-scaled for pure-sum aggregation)
// Block: 32 rows, 4 waves = 2 row-halves x 2 col-halves. Wave: 16 rows x 64 cols.

template<bool TRANS>
__global__ __launch_bounds__(256) void gemm_kernel(
    const void* __restrict__ Av, const unsigned short* __restrict__ Wpk,
    const float* __restrict__ sums, const float* __restrict__ gamma, const float* __restrict__ beta,
    const float* __restrict__ dinv, unsigned short* __restrict__ out)
{
    int tid = threadIdx.x;
    int wv = tid >> 6, l = tid & 63;
    int m = l & 15, kg = l >> 4;
    int rhalf = wv & 1, chalf = wv >> 1;
    int row = blockIdx.x * 32 + rhalf * 16 + m;
    int rowc = min(row, NN - 1);

    f32x4 acc[4] = {};

    #pragma unroll
    for (int kt = 0; kt < 4; ++kt) {
        int k0 = kt * 32 + kg * 8;
        bf16x8 af;
        if (TRANS) {
            const unsigned short* Ar = (const unsigned short*)Av + (size_t)rowc * C;
            u16x8 raw = *(const u16x8*)&Ar[k0];
            #pragma unroll
            for (int j = 0; j < 8; ++j) {
                int k = k0 + j;
                float mean = sums[k] * INVN;
                float var = fmaf(-mean, mean, sums[128 + k] * INVN);
                float sc = gamma[k] * rsqrtf(var + BN_EPS);
                float sh = fmaf(-mean, sc, beta[k]);
                af[j] = (short)f2bf(fmaxf(fmaf(bf2f(raw[j]), sc, sh), 0.f));
            }
        } else {
            const float* Ar = (const float*)Av + (size_t)rowc * C;
            float4 x0 = *(const float4*)&Ar[k0];
            float4 x1 = *(const float4*)&Ar[k0 + 4];
            af[0] = (short)f2bf(x0.x); af[1] = (short)f2bf(x0.y);
            af[2] = (short)f2bf(x0.z); af[3] = (short)f2bf(x0.w);
            af[4] = (short)f2bf(x1.x); af[5] = (short)f2bf(x1.y);
            af[6] = (short)f2bf(x1.z); af[7] = (short)f2bf(x1.w);
        }
        #pragma unroll
        for (int n = 0; n < 4; ++n) {
            int nt = chalf * 4 + n;
            bf16x8 bfr = *(const bf16x8*)&Wpk[(size_t)((kt * 8 + nt) * 64 + l) * 8];
            acc[n] = __builtin_amdgcn_mfma_f32_16x16x32_bf16(af, bfr, acc[n], 0, 0, 0);
        }
    }

    // D: lane l holds D[(l>>4)*4 + r][nt*16 + (l&15)]
    int ro = blockIdx.x * 32 + rhalf * 16 + kg * 4;
    #pragma unroll
    for (int r = 0; r < 4; ++r) {
        int orow = ro + r;
        if (orow < NN) {
            float di = dinv[orow];
            #pragma unroll
            for (int n = 0; n < 4; ++n)
                out[(size_t)orow * C + (chalf * 4 + n) * 16 + m] = f2bf(di * acc[n][r]);
        }
    }
}

// ---------------- Pull aggregation from bf16 table, 4 edges per gather instr ----------------
// Wave per row. lane = eg(=l>>4: edge slot) x q(=l&15: channel-8th, ch q*8..q*8+7).
// Per batch of 16 edges: 4 gathers of ushort8 (16B/lane, 1KB/instr = 4 edge-rows).
// !SPLIT: out bf16 [NN][128] (aggb).  SPLIT: heads - f32 split 64|64 + bias.

template<bool SPLIT>
__global__ __launch_bounds__(256) void agg_kernel(
    const unsigned short* __restrict__ t, const int* __restrict__ rowptr, const int* __restrict__ col,
    const float* __restrict__ dinv, const float* __restrict__ bmu, const float* __restrict__ bls,
    unsigned short* __restrict__ outb16, float* __restrict__ outmu, float* __restrict__ outls)
{
    int wave = threadIdx.x >> 6, lane = threadIdx.x & 63;
    int row = blockIdx.x * 4 + wave;     // NN % 4 == 0: no guard
    int q = lane & 15, eg = lane >> 4;
    const unsigned short* tq = t + q * 8;
    int e0 = rowptr[row], e1 = rowptr[row + 1];
    float a[8] = {};

    for (int e = e0; e < e1; e += 16) {
        int lim = e1 - 1;
        u16x8 v[4];
        float msk[4];
        #pragma unroll
        for (int b = 0; b < 4; ++b) {
            int i = e + b * 4 + eg;
            msk[b] = (i < e1) ? 1.f : 0.f;
            if (e + b * 4 < e1) {                       // wave-uniform batch-live check
                int s = col[min(i, lim)];
                v[b] = *(const u16x8*)&tq[(size_t)s * C];
            } else {
                v[b] = (u16x8)0;
                msk[b] = 0.f;
            }
        }
        #pragma unroll
        for (int b = 0; b < 4; ++b) {
            #pragma unroll
            for (int j = 0; j < 8; ++j)
                a[j] = fmaf(msk[b], bf2f(v[b][j]), a[j]);
        }
    }

    {   // self-loop: counted once (eg==0 lanes only)
        u16x8 vs = *(const u16x8*)&tq[(size_t)row * C];
        float ms = (eg == 0) ? 1.f : 0.f;
        #pragma unroll
        for (int j = 0; j < 8; ++j)
            a[j] = fmaf(ms, bf2f(vs[j]), a[j]);
    }

    #pragma unroll
    for (int j = 0; j < 8; ++j) {
        a[j] += __shfl_xor(a[j], 16);
        a[j] += __shfl_xor(a[j], 32);
    }

    if (eg == 0) {
        float di = dinv[row];
        int c = q * 8;
        if (!SPLIT) {
            u16x8 o;
            #pragma unroll
            for (int j = 0; j < 8; ++j) o[j] = f2bf(di * a[j]);
            *(u16x8*)&outb16[(size_t)row * C + c] = o;
        } else {
            if (c < 64) {
                float4 b0 = *(const float4*)&bmu[c];
                float4 b1 = *(const float4*)&bmu[c + 4];
                *(float4*)&outmu[(size_t)row * OUTC + c]
                    = make_float4(fmaf(di,a[0],b0.x), fmaf(di,a[1],b0.y), fmaf(di,a[2],b0.z), fmaf(di,a[3],b0.w));
                *(float4*)&outmu[(size_t)row * OUTC + c + 4]
                    = make_float4(fmaf(di,a[4],b1.x), fmaf(di,a[5],b1.y), fmaf(di,a[6],b1.z), fmaf(di,a[7],b1.w));
            } else {
                int cc = c - 64;
                float4 b0 = *(const float4*)&bls[cc];
                float4 b1 = *(const float4*)&bls[cc + 4];
                *(float4*)&outls[(size_t)row * OUTC + cc]
                    = make_float4(fmaf(di,a[0],b0.x), fmaf(di,a[1],b0.y), fmaf(di,a[2],b0.z), fmaf(di,a[3],b0.w));
                *(float4*)&outls[(size_t)row * OUTC + cc + 4]
                    = make_float4(fmaf(di,a[4],b1.x), fmaf(di,a[5],b1.y), fmaf(di,a[6],b1.z), fmaf(di,a[7],b1.w));
            }
        }
    }
}

// ---------------- BatchNorm stats (bf16 row-major input) ----------------

__global__ __launch_bounds__(256) void bnstats_kernel(const unsigned short* __restrict__ h, float* __restrict__ sums) {
    int c = threadIdx.x & 127;
    int hh = threadIdx.x >> 7;
    float s = 0.f, sq = 0.f;
    for (int r = blockIdx.x * 2 + hh; r < NN; r += gridDim.x * 2) {
        float v = bf2f(h[(size_t)r * C + c]);
        s += v; sq = fmaf(v, v, sq);
    }
    __shared__ float ls[256], lq[256];
    ls[threadIdx.x] = s; lq[threadIdx.x] = sq;
    __syncthreads();
    if (hh == 0) {
        atomicAdd(&sums[c], s + ls[c + 128]);
        atomicAdd(&sums[128 + c], sq + lq[c + 128]);
    }
}

// ---------------- launch ----------------

extern "C" void kernel_launch(void* const* d_in, const int* in_sizes, int n_in,
                              void* d_out, int out_size, void* d_ws, size_t ws_size,
                              hipStream_t stream) {
    (void)in_sizes; (void)n_in; (void)out_size; (void)ws_size;
    const float* x      = (const float*)d_in[0];
    const int*   ei     = (const int*)d_in[1];
    const float* W1     = (const float*)d_in[2];
    // d_in[3] = b1: cancelled exactly by BN mean-subtraction
    const float* gamma1 = (const float*)d_in[4];
    const float* beta1  = (const float*)d_in[5];
    const float* W2     = (const float*)d_in[6];
    // d_in[7] = b2: cancelled exactly by BN
    const float* gamma2 = (const float*)d_in[8];
    const float* beta2  = (const float*)d_in[9];
    const float* Wmu    = (const float*)d_in[10];
    const float* bmu    = (const float*)d_in[11];
    const float* Wls    = (const float*)d_in[12];
    const float* bls    = (const float*)d_in[13];

    float* outmu = (float*)d_out;
    float* outls = outmu + (size_t)NN * OUTC;

    char* w = (char*)d_ws;
    size_t off = 0;
    auto alloc = [&](size_t bytes) { char* p = w + off; off = (off + bytes + 255) & ~(size_t)255; return p; };
    unsigned short* t    = (unsigned short*)alloc(sizeof(unsigned short) * NN * C);  // 12.8 MB bf16
    unsigned short* aggb = (unsigned short*)alloc(sizeof(unsigned short) * NN * C);  // 12.8 MB bf16
    int*   cnt    = (int*)  alloc(sizeof(int) * NN);
    float* sums   = (float*)alloc(sizeof(float) * 512);          // adjacent to cnt: one memset covers both
    int*   rowptr = (int*)  alloc(sizeof(int) * (NN + 1));
    int*   wpos   = (int*)  alloc(sizeof(int) * NN);
    int*   col    = (int*)  alloc(sizeof(int) * NE);
    float* dinv   = (float*)alloc(sizeof(float) * NN);
    int*   bsum   = (int*)  alloc(sizeof(int) * 64);
    int*   pc     = (int*)  alloc(sizeof(int) * NCHUNK * 8);
    int*   po     = (int*)  alloc(sizeof(int) * NCHUNK * 8);
    unsigned long long* part = (unsigned long long*)alloc(sizeof(unsigned long long) * NE);  // 6.4 MB
    unsigned short* Wpk = (unsigned short*)alloc(sizeof(unsigned short) * 3 * 16384);        // 96 KB
    float* sumsA = sums; float* sumsB = sums + 256;

    const int* srcp = ei;
    const int* dstp = ei + NE;

    size_t zspan = (size_t)((char*)(sums + 512) - (char*)cnt);
    hipMemsetAsync(cnt, 0, zspan, stream);

    pcount_kernel<<<NCHUNK, 256, 0, stream>>>(dstp, pc);
    pscan_kernel<<<1, 256, 0, stream>>>(pc, po);
    ppart_kernel<<<NCHUNK, 256, 0, stream>>>(srcp, dstp, po, part, cnt);
    scan1_kernel<<<NBLK, 256, 0, stream>>>(cnt, rowptr, dinv, bsum);
    scan3_kernel<<<NBLK, 256, 0, stream>>>(bsum, rowptr, wpos);
    fill2_kernel<<<NSH * FB, 256, 0, stream>>>(part, po, wpos, col);
    prep_kernel<<<24, 256, 0, stream>>>(W1, W2, Wmu, Wls, Wpk);

    const int GB = (NN + 31) / 32;
    const int AB = NN / 4;

    // layer 1: t = bf16(dinv .* (x@W1)) ; aggb = aggregate(bf16) ; BN1 stats
    gemm_kernel<false><<<GB, 256, 0, stream>>>(x, Wpk, nullptr, nullptr, nullptr, dinv, t);
    agg_kernel<false><<<AB, 256, 0, stream>>>(t, rowptr, col, dinv, nullptr, nullptr, aggb, nullptr, nullptr);
    bnstats_kernel<<<400, 256, 0, stream>>>(aggb, sumsA);

    // layer 2: t = bf16(dinv .* (relu(BN1(aggb))@W2)) ; aggb = aggregate(bf16) ; BN2 stats
    gemm_kernel<true><<<GB, 256, 0, stream>>>(aggb, Wpk + 16384, sumsA, gamma1, beta1, dinv, t);
    agg_kernel<false><<<AB, 256, 0, stream>>>(t, rowptr, col, dinv, nullptr, nullptr, aggb, nullptr, nullptr);
    bnstats_kernel<<<400, 256, 0, stream>>>(aggb, sumsB);

    // heads (reassociated): t = bf16(dinv .* (relu(BN2(aggb)) @ [Wmu|Wls])) ; agg3 -> split + bias
    gemm_kernel<true><<<GB, 256, 0, stream>>>(aggb, Wpk + 32768, sumsB, gamma2, beta2, dinv, t);
    agg_kernel<true><<<AB, 256, 0, stream>>>(t, rowptr, col, dinv, bmu, bls, nullptr, outmu, outls);
}

// Round 11
// 373.903 us; speedup vs baseline: 1.0622x; 1.0622x over previous
//
#include <hip/hip_runtime.h>

#define NN 50000
#define NE 800000
#define C 128
#define OUTC 64
#define BN_EPS 1e-5f
#define INVN (1.0f / 50000.0f)
#define NBLK 49        // ceil(NN/1024)
#define NSH 8          // dst-range shards (= XCDs)
#define SHW (NN / NSH) // 6250 dst rows per shard
#define NCHUNK 256
#define CHUNK (NE / NCHUNK) // 3125 edges per chunk
#define FB 32          // fill2/cntloc blocks per shard

typedef __attribute__((ext_vector_type(8))) short bf16x8;
typedef __attribute__((ext_vector_type(4))) float f32x4;
typedef __attribute__((ext_vector_type(8))) unsigned short u16x8;

// round-to-nearest-even f32 -> bf16 (finite values)
__device__ __forceinline__ unsigned short f2bf(float f) {
    unsigned u = __float_as_uint(f);
    u += 0x7fffu + ((u >> 16) & 1u);
    return (unsigned short)(u >> 16);
}
__device__ __forceinline__ float bf2f(unsigned short s) {
    return __uint_as_float((unsigned)s << 16);
}

// ---------------- CSR build: counting sort with XCD-local shard partition ----------------

// per-chunk shard histogram: pc[chunk][shard]
__global__ __launch_bounds__(256) void pcount_kernel(const int* __restrict__ dstp, int* __restrict__ pc) {
    __shared__ int lc[8];
    int tid = threadIdx.x, mb = blockIdx.x;
    if (tid < 8) lc[tid] = 0;
    __syncthreads();
    int end = (mb + 1) * CHUNK;
    for (int e = mb * CHUNK + tid; e < end; e += 256)
        atomicAdd(&lc[dstp[e] / SHW], 1);
    __syncthreads();
    if (tid < 8) pc[mb * 8 + tid] = lc[tid];
}

// exclusive scan over 2048 (shard-major: i = g*NCHUNK + m) -> po[i]
__global__ __launch_bounds__(256) void pscan_kernel(const int* __restrict__ pc, int* __restrict__ po) {
    __shared__ int lds[256];
    int t = threadIdx.x;
    int v[8], s = 0;
    #pragma unroll
    for (int j = 0; j < 8; ++j) {
        int i = t * 8 + j;
        v[j] = pc[(i & (NCHUNK - 1)) * 8 + (i >> 8)];
        s += v[j];
    }
    lds[t] = s;
    __syncthreads();
    for (int off = 1; off < 256; off <<= 1) {
        int x = (t >= off) ? lds[t - off] : 0;
        __syncthreads();
        lds[t] += x;
        __syncthreads();
    }
    int excl = lds[t] - s;
    #pragma unroll
    for (int j = 0; j < 8; ++j) { po[t * 8 + j] = excl; excl += v[j]; }
}

// partition edges into shard segments (disjoint per (chunk,shard)); NO cnt atomics here
__global__ __launch_bounds__(256) void ppart_kernel(const int* __restrict__ srcp, const int* __restrict__ dstp,
                                                    const int* __restrict__ po,
                                                    unsigned long long* __restrict__ part) {
    __shared__ int base[8], ctr[8];
    int tid = threadIdx.x, mb = blockIdx.x;
    if (tid < 8) { base[tid] = po[tid * NCHUNK + mb]; ctr[tid] = 0; }
    __syncthreads();
    int end = (mb + 1) * CHUNK;
    for (int e = mb * CHUNK + tid; e < end; e += 256) {
        int d = dstp[e], s = srcp[e];
        int g = d / SHW;
        int slot = atomicAdd(&ctr[g], 1);            // LDS
        part[(size_t)(base[g] + slot)] = ((unsigned long long)(unsigned)d << 32) | (unsigned)s;
    }
}

// per-dst counts from the dst-sharded partition: all cnt atomics XCD-local
__global__ __launch_bounds__(256) void cntloc_kernel(const unsigned long long* __restrict__ part,
                                                     const int* __restrict__ po, int* __restrict__ cnt) {
    int g = blockIdx.x & 7, ib = blockIdx.x >> 3;
    int lo = po[g * NCHUNK];
    int hi = (g == 7) ? NE : po[(g + 1) * NCHUNK];
    for (int idx = lo + ib * 256 + threadIdx.x; idx < hi; idx += FB * 256)
        atomicAdd(&cnt[(int)(part[idx] >> 32)], 1);
}

__global__ __launch_bounds__(256) void scan1_kernel(const int* __restrict__ cnt, int* __restrict__ rowptr,
                                                    float* __restrict__ dinv, int* __restrict__ bsum) {
    __shared__ int lds[256];
    int tid = threadIdx.x;
    int base = blockIdx.x * 1024 + tid * 4;
    int v[4];
    int s = 0;
    #pragma unroll
    for (int j = 0; j < 4; ++j) { int i = base + j; v[j] = (i < NN) ? cnt[i] : 0; s += v[j]; }
    lds[tid] = s;
    __syncthreads();
    for (int off = 1; off < 256; off <<= 1) {
        int x = (tid >= off) ? lds[tid - off] : 0;
        __syncthreads();
        lds[tid] += x;
        __syncthreads();
    }
    int excl = lds[tid] - s;
    #pragma unroll
    for (int j = 0; j < 4; ++j) {
        int i = base + j;
        if (i < NN) {
            rowptr[i] = excl;                       // local exclusive; block offset added in scan3
            dinv[i] = rsqrtf((float)(v[j] + 1));    // +1 self-loop
        }
        excl += v[j];
    }
    if (tid == 255) bsum[blockIdx.x] = lds[255];
}

// adds block offsets (inline 49-element scan of bsum), mirrors into wpos
__global__ __launch_bounds__(256) void scan3_kernel(const int* __restrict__ bsum, int* __restrict__ rowptr,
                                                    int* __restrict__ wpos) {
    __shared__ int boff;
    int tid = threadIdx.x;
    if (tid < 64) {
        int orig = (tid < NBLK) ? bsum[tid] : 0;
        int v = orig;
        #pragma unroll
        for (int off = 1; off < 64; off <<= 1) {
            int x = __shfl_up(v, off);
            if (tid >= off) v += x;
        }
        if (tid == (int)blockIdx.x) boff = v - orig;   // exclusive prefix at this block
    }
    __syncthreads();
    int off = boff;
    int base = blockIdx.x * 1024 + tid * 4;
    #pragma unroll
    for (int j = 0; j < 4; ++j) {
        int i = base + j;
        if (i < NN) { int r = rowptr[i] + off; rowptr[i] = r; wpos[i] = r; }
    }
    if (blockIdx.x == 0 && tid == 0) rowptr[NN] = NE;
}

// scatter src into CSR col; everything (segment read, wpos atomics, col writes) XCD-local
__global__ __launch_bounds__(256) void fill2_kernel(const unsigned long long* __restrict__ part,
                                                    const int* __restrict__ po,
                                                    int* __restrict__ wpos, int* __restrict__ col) {
    int g = blockIdx.x & 7, ib = blockIdx.x >> 3;
    int lo = po[g * NCHUNK];
    int hi = (g == 7) ? NE : po[(g + 1) * NCHUNK];
    for (int idx = lo + ib * 256 + threadIdx.x; idx < hi; idx += FB * 256) {
        unsigned long long pk = part[idx];
        int d = (int)(pk >> 32), s = (int)(pk & 0xffffffffu);
        int p = atomicAdd(&wpos[d], 1);
        col[p] = s;
    }
}

// ---------------- W pre-pack: bf16, MFMA B-fragment layout ----------------
// Wpk[mat][kt(4)][nt(8)][lane(64)][8 bf16]: lane holds W[kt*32 + (lane>>4)*8 + j][nt*16 + (lane&15)]
// mat 0 = W1, 1 = W2, 2 = [Wmu|Wls]

__global__ __launch_bounds__(256) void prep_kernel(const float* __restrict__ W1, const float* __restrict__ W2,
                                                   const float* __restrict__ Wmu, const float* __restrict__ Wls,
                                                   unsigned short* __restrict__ Wpk) {
    int idx = blockIdx.x * 256 + threadIdx.x;    // 0..6143
    if (idx >= 3 * 2048) return;
    int which = idx >> 11;
    int r = idx & 2047;
    int l = r & 63;
    int nt = (r >> 6) & 7;
    int kt = r >> 9;
    int m = l & 15, kg = l >> 4;
    int c = nt * 16 + m;
    bf16x8 o;
    #pragma unroll
    for (int j = 0; j < 8; ++j) {
        int k = kt * 32 + kg * 8 + j;
        float w;
        if (which == 0)      w = W1[k * 128 + c];
        else if (which == 1) w = W2[k * 128 + c];
        else                 w = (c < 64) ? Wmu[k * 64 + c] : Wls[k * 64 + (c - 64)];
        o[j] = (short)f2bf(w);
    }
    *(bf16x8*)&Wpk[(size_t)which * 16384 + (size_t)r * 8] = o;
}

// ---------------- GEMM: [N x 128] @ [128 x 128] via bf16 MFMA, f32 accum ----------------
// TRANS: input bf16 aggb; apply precomputed BN scale/shift + ReLU, re-encode bf16
// !TRANS: input f32 x
// Output: t[row][c] = bf16(dinv[row] * acc)  (pre-scaled for pure-sum aggregation)
// Block: 32 rows, 4 waves = 2 row-halves x 2 col-halves. Wave: 16 rows x 64 cols.

template<bool TRANS>
__global__ __launch_bounds__(256) void gemm_kernel(
    const void* __restrict__ Av, const unsigned short* __restrict__ Wpk,
    const float* __restrict__ scale, const float* __restrict__ shift,
    const float* __restrict__ dinv, unsigned short* __restrict__ out)
{
    int tid = threadIdx.x;
    int wv = tid >> 6, l = tid & 63;
    int m = l & 15, kg = l >> 4;
    int rhalf = wv & 1, chalf = wv >> 1;
    int row = blockIdx.x * 32 + rhalf * 16 + m;
    int rowc = min(row, NN - 1);

    f32x4 acc[4] = {};

    #pragma unroll
    for (int kt = 0; kt < 4; ++kt) {
        int k0 = kt * 32 + kg * 8;
        bf16x8 af;
        if (TRANS) {
            const unsigned short* Ar = (const unsigned short*)Av + (size_t)rowc * C;
            u16x8 raw = *(const u16x8*)&Ar[k0];
            float4 sc0 = *(const float4*)&scale[k0];
            float4 sc1 = *(const float4*)&scale[k0 + 4];
            float4 sh0 = *(const float4*)&shift[k0];
            float4 sh1 = *(const float4*)&shift[k0 + 4];
            float scv[8] = {sc0.x, sc0.y, sc0.z, sc0.w, sc1.x, sc1.y, sc1.z, sc1.w};
            float shv[8] = {sh0.x, sh0.y, sh0.z, sh0.w, sh1.x, sh1.y, sh1.z, sh1.w};
            #pragma unroll
            for (int j = 0; j < 8; ++j)
                af[j] = (short)f2bf(fmaxf(fmaf(bf2f(raw[j]), scv[j], shv[j]), 0.f));
        } else {
            const float* Ar = (const float*)Av + (size_t)rowc * C;
            float4 x0 = *(const float4*)&Ar[k0];
            float4 x1 = *(const float4*)&Ar[k0 + 4];
            af[0] = (short)f2bf(x0.x); af[1] = (short)f2bf(x0.y);
            af[2] = (short)f2bf(x0.z); af[3] = (short)f2bf(x0.w);
            af[4] = (short)f2bf(x1.x); af[5] = (short)f2bf(x1.y);
            af[6] = (short)f2bf(x1.z); af[7] = (short)f2bf(x1.w);
        }
        #pragma unroll
        for (int n = 0; n < 4; ++n) {
            int nt = chalf * 4 + n;
            bf16x8 bfr = *(const bf16x8*)&Wpk[(size_t)((kt * 8 + nt) * 64 + l) * 8];
            acc[n] = __builtin_amdgcn_mfma_f32_16x16x32_bf16(af, bfr, acc[n], 0, 0, 0);
        }
    }

    // D: lane l holds D[(l>>4)*4 + r][nt*16 + (l&15)]
    int ro = blockIdx.x * 32 + rhalf * 16 + kg * 4;
    #pragma unroll
    for (int r = 0; r < 4; ++r) {
        int orow = ro + r;
        if (orow < NN) {
            float di = dinv[orow];
            #pragma unroll
            for (int n = 0; n < 4; ++n)
                out[(size_t)orow * C + (chalf * 4 + n) * 16 + m] = f2bf(di * acc[n][r]);
        }
    }
}

// ---------------- Pull aggregation from bf16 table, 32-edge batches ----------------
// Wave per row. lane = eg(=l>>4: edge slot in subbatch) x q(=l&15: channel-8th).
// Per batch of 32 edges: 8 gathers of ushort8 (16B/lane, 1KB/instr = 4 edge-rows) in flight.
// !SPLIT: out bf16 [NN][128] (aggb).  SPLIT: heads - f32 split 64|64 + bias.

template<bool SPLIT>
__global__ __launch_bounds__(256) void agg_kernel(
    const unsigned short* __restrict__ t, const int* __restrict__ rowptr, const int* __restrict__ col,
    const float* __restrict__ dinv, const float* __restrict__ bmu, const float* __restrict__ bls,
    unsigned short* __restrict__ outb16, float* __restrict__ outmu, float* __restrict__ outls)
{
    int wave = threadIdx.x >> 6, lane = threadIdx.x & 63;
    int row = blockIdx.x * 4 + wave;     // NN % 4 == 0: no guard
    int q = lane & 15, eg = lane >> 4;
    const unsigned short* tq = t + q * 8;
    int e0 = rowptr[row], e1 = rowptr[row + 1];
    float a[8] = {};

    for (int e = e0; e < e1; e += 32) {
        int lim = e1 - 1;
        u16x8 v[8];
        float msk[8];
        #pragma unroll
        for (int b = 0; b < 8; ++b) {
            int i = e + b * 4 + eg;
            if (e + b * 4 < e1) {                       // wave-uniform subbatch-live check
                int s = col[min(i, lim)];
                v[b] = *(const u16x8*)&tq[(size_t)s * C];
                msk[b] = (i < e1) ? 1.f : 0.f;
            } else {
                v[b] = (u16x8)0;
                msk[b] = 0.f;
            }
        }
        #pragma unroll
        for (int b = 0; b < 8; ++b) {
            #pragma unroll
            for (int j = 0; j < 8; ++j)
                a[j] = fmaf(msk[b], bf2f(v[b][j]), a[j]);
        }
    }

    {   // self-loop: counted once (eg==0 lanes only)
        u16x8 vs = *(const u16x8*)&tq[(size_t)row * C];
        float ms = (eg == 0) ? 1.f : 0.f;
        #pragma unroll
        for (int j = 0; j < 8; ++j)
            a[j] = fmaf(ms, bf2f(vs[j]), a[j]);
    }

    #pragma unroll
    for (int j = 0; j < 8; ++j) {
        a[j] += __shfl_xor(a[j], 16);
        a[j] += __shfl_xor(a[j], 32);
    }

    if (eg == 0) {
        float di = dinv[row];
        int c = q * 8;
        if (!SPLIT) {
            u16x8 o;
            #pragma unroll
            for (int j = 0; j < 8; ++j) o[j] = f2bf(di * a[j]);
            *(u16x8*)&outb16[(size_t)row * C + c] = o;
        } else {
            if (c < 64) {
                float4 b0 = *(const float4*)&bmu[c];
                float4 b1 = *(const float4*)&bmu[c + 4];
                *(float4*)&outmu[(size_t)row * OUTC + c]
                    = make_float4(fmaf(di,a[0],b0.x), fmaf(di,a[1],b0.y), fmaf(di,a[2],b0.z), fmaf(di,a[3],b0.w));
                *(float4*)&outmu[(size_t)row * OUTC + c + 4]
                    = make_float4(fmaf(di,a[4],b1.x), fmaf(di,a[5],b1.y), fmaf(di,a[6],b1.z), fmaf(di,a[7],b1.w));
            } else {
                int cc = c - 64;
                float4 b0 = *(const float4*)&bls[cc];
                float4 b1 = *(const float4*)&bls[cc + 4];
                *(float4*)&outls[(size_t)row * OUTC + cc]
                    = make_float4(fmaf(di,a[0],b0.x), fmaf(di,a[1],b0.y), fmaf(di,a[2],b0.z), fmaf(di,a[3],b0.w));
                *(float4*)&outls[(size_t)row * OUTC + cc + 4]
                    = make_float4(fmaf(di,a[4],b1.x), fmaf(di,a[5],b1.y), fmaf(di,a[6],b1.z), fmaf(di,a[7],b1.w));
            }
        }
    }
}

// ---------------- BatchNorm stats (bf16 input, vectorized u16x8) ----------------
// thread = (rslot = tid>>4, c8 = tid&15); accumulates 8 channels over rows; LDS reduce over rslots

__global__ __launch_bounds__(256) void bnstats_kernel(const unsigned short* __restrict__ h, float* __restrict__ sums) {
    __shared__ float ls[16][128], lq[16][128];
    int c8 = threadIdx.x & 15, rs = threadIdx.x >> 4;
    float s[8] = {}, sq[8] = {};
    for (int r = blockIdx.x * 16 + rs; r < NN; r += gridDim.x * 16) {
        u16x8 v = *(const u16x8*)&h[(size_t)r * C + c8 * 8];
        #pragma unroll
        for (int j = 0; j < 8; ++j) {
            float f = bf2f(v[j]);
            s[j] += f; sq[j] = fmaf(f, f, sq[j]);
        }
    }
    #pragma unroll
    for (int j = 0; j < 8; ++j) { ls[rs][c8 * 8 + j] = s[j]; lq[rs][c8 * 8 + j] = sq[j]; }
    __syncthreads();
    int tid = threadIdx.x;
    if (tid < 128) {
        float acc = 0.f;
        #pragma unroll
        for (int p = 0; p < 16; ++p) acc += ls[p][tid];
        atomicAdd(&sums[tid], acc);
    } else {
        int c = tid - 128;
        float acc = 0.f;
        #pragma unroll
        for (int p = 0; p < 16; ++p) acc += lq[p][c];
        atomicAdd(&sums[128 + c], acc);
    }
}

// ---------------- BN finalize: raw sums -> scale/shift ----------------

__global__ __launch_bounds__(128) void bnfin_kernel(const float* __restrict__ sums,
                                                    const float* __restrict__ gamma, const float* __restrict__ beta,
                                                    float* __restrict__ scale, float* __restrict__ shift) {
    int c = threadIdx.x;
    float mean = sums[c] * INVN;
    float var = fmaf(-mean, mean, sums[128 + c] * INVN);
    float s = gamma[c] * rsqrtf(var + BN_EPS);
    scale[c] = s;
    shift[c] = fmaf(-mean, s, beta[c]);
}

// ---------------- launch ----------------

extern "C" void kernel_launch(void* const* d_in, const int* in_sizes, int n_in,
                              void* d_out, int out_size, void* d_ws, size_t ws_size,
                              hipStream_t stream) {
    (void)in_sizes; (void)n_in; (void)out_size; (void)ws_size;
    const float* x      = (const float*)d_in[0];
    const int*   ei     = (const int*)d_in[1];
    const float* W1     = (const float*)d_in[2];
    // d_in[3] = b1: cancelled exactly by BN mean-subtraction
    const float* gamma1 = (const float*)d_in[4];
    const float* beta1  = (const float*)d_in[5];
    const float* W2     = (const float*)d_in[6];
    // d_in[7] = b2: cancelled exactly by BN
    const float* gamma2 = (const float*)d_in[8];
    const float* beta2  = (const float*)d_in[9];
    const float* Wmu    = (const float*)d_in[10];
    const float* bmu    = (const float*)d_in[11];
    const float* Wls    = (const float*)d_in[12];
    const float* bls    = (const float*)d_in[13];

    float* outmu = (float*)d_out;
    float* outls = outmu + (size_t)NN * OUTC;

    char* w = (char*)d_ws;
    size_t off = 0;
    auto alloc = [&](size_t bytes) { char* p = w + off; off = (off + bytes + 255) & ~(size_t)255; return p; };
    unsigned short* t    = (unsigned short*)alloc(sizeof(unsigned short) * NN * C);  // 12.8 MB bf16
    unsigned short* aggb = (unsigned short*)alloc(sizeof(unsigned short) * NN * C);  // 12.8 MB bf16
    int*   cnt    = (int*)  alloc(sizeof(int) * NN);
    float* sums   = (float*)alloc(sizeof(float) * 512);          // adjacent to cnt: one memset covers both
    int*   rowptr = (int*)  alloc(sizeof(int) * (NN + 1));
    int*   wpos   = (int*)  alloc(sizeof(int) * NN);
    int*   col    = (int*)  alloc(sizeof(int) * NE);
    float* dinv   = (float*)alloc(sizeof(float) * NN);
    int*   bsum   = (int*)  alloc(sizeof(int) * 64);
    int*   pc     = (int*)  alloc(sizeof(int) * NCHUNK * 8);
    int*   po     = (int*)  alloc(sizeof(int) * NCHUNK * 8);
    unsigned long long* part = (unsigned long long*)alloc(sizeof(unsigned long long) * NE);  // 6.4 MB
    unsigned short* Wpk = (unsigned short*)alloc(sizeof(unsigned short) * 3 * 16384);        // 96 KB
    float* scale1 = (float*)alloc(512);
    float* shift1 = (float*)alloc(512);
    float* scale2 = (float*)alloc(512);
    float* shift2 = (float*)alloc(512);
    float* sumsA = sums; float* sumsB = sums + 256;

    const int* srcp = ei;
    const int* dstp = ei + NE;

    size_t zspan = (size_t)((char*)(sums + 512) - (char*)cnt);
    hipMemsetAsync(cnt, 0, zspan, stream);

    pcount_kernel<<<NCHUNK, 256, 0, stream>>>(dstp, pc);
    pscan_kernel<<<1, 256, 0, stream>>>(pc, po);
    ppart_kernel<<<NCHUNK, 256, 0, stream>>>(srcp, dstp, po, part);
    cntloc_kernel<<<NSH * FB, 256, 0, stream>>>(part, po, cnt);
    scan1_kernel<<<NBLK, 256, 0, stream>>>(cnt, rowptr, dinv, bsum);
    scan3_kernel<<<NBLK, 256, 0, stream>>>(bsum, rowptr, wpos);
    fill2_kernel<<<NSH * FB, 256, 0, stream>>>(part, po, wpos, col);
    prep_kernel<<<24, 256, 0, stream>>>(W1, W2, Wmu, Wls, Wpk);

    const int GB = (NN + 31) / 32;
    const int AB = NN / 4;

    // layer 1: t = bf16(dinv .* (x@W1)) ; aggb = aggregate(bf16) ; BN1 stats -> scale/shift
    gemm_kernel<false><<<GB, 256, 0, stream>>>(x, Wpk, nullptr, nullptr, dinv, t);
    agg_kernel<false><<<AB, 256, 0, stream>>>(t, rowptr, col, dinv, nullptr, nullptr, aggb, nullptr, nullptr);
    bnstats_kernel<<<100, 256, 0, stream>>>(aggb, sumsA);
    bnfin_kernel<<<1, 128, 0, stream>>>(sumsA, gamma1, beta1, scale1, shift1);

    // layer 2: t = bf16(dinv .* (relu(BN1(aggb))@W2)) ; aggb = aggregate(bf16) ; BN2 stats
    gemm_kernel<true><<<GB, 256, 0, stream>>>(aggb, Wpk + 16384, scale1, shift1, dinv, t);
    agg_kernel<false><<<AB, 256, 0, stream>>>(t, rowptr, col, dinv, nullptr, nullptr, aggb, nullptr, nullptr);
    bnstats_kernel<<<100, 256, 0, stream>>>(aggb, sumsB);
    bnfin_kernel<<<1, 128, 0, stream>>>(sumsB, gamma2, beta2, scale2, shift2);

    // heads (reassociated): t = bf16(dinv .* (relu(BN2(aggb)) @ [Wmu|Wls])) ; agg3 -> split + bias
    gemm_kernel<true><<<GB, 256, 0, stream>>>(aggb, Wpk + 32768, scale2, shift2, dinv, t);
    agg_kernel<true><<<AB, 256, 0, stream>>>(t, rowptr, col, dinv, bmu, bls, nullptr, outmu, outls);
}